// Round 1
// baseline (6061.884 us; speedup 1.0000x reference)
//
#include <hip/hip_runtime.h>

// TimeLSTM persistent-scan kernel for MI355X (gfx950).
// Grid: 128 blocks x 320 threads. grp = blockIdx&3 owns batches grp*16..+15;
// member = blockIdx>>2 owns columns member*16..+15 of each gate and of W_d.
// Weights are preloaded into VGPRs as f16 MFMA B-fragments and reused for all
// 1024 time steps. h/c are exchanged between the 32 wgs of a group each step
// via a double-buffered global f16 buffer + device-scope atomic barrier.

typedef _Float16 f16;
typedef _Float16 f16x8 __attribute__((ext_vector_type(8)));
typedef float f32x4 __attribute__((ext_vector_type(4)));

#define S_ 1024
#define IN_ 256
#define H_ 512
#define ECONST 2.718281828459045f

__device__ __forceinline__ float sigf(float x) { return 1.0f / (1.0f + __expf(-x)); }
// tanh via exp; saturates correctly at +-1 for large |x|
__device__ __forceinline__ float tanh_f(float x) { return 1.0f - 2.0f / (__expf(2.0f * x) + 1.0f); }

__launch_bounds__(320, 2)
__global__ void tlstm_scan(
    const float* __restrict__ inputs, const float* __restrict__ tstamps,
    const int* __restrict__ lens,
    const float* __restrict__ W_all, const float* __restrict__ b_all,
    const float* __restrict__ U_all, const float* __restrict__ b_u,
    const float* __restrict__ W_d, const float* __restrict__ b_d,
    float* __restrict__ out0, float* __restrict__ out1, float* __restrict__ out2,
    f16* __restrict__ hbuf, f16* __restrict__ cbuf, unsigned int* __restrict__ cnt)
{
    // LDS: A operand (h: kb 0..63, x_t: kb 64..95) and c operand in MFMA
    // fragment-friendly interleave [kb][m][8] (2-way bank aliasing = free).
    __shared__ __align__(16) f16 A_sm[96 * 16 * 8];   // 24 KB
    __shared__ __align__(16) f16 C_sm[64 * 16 * 8];   // 16 KB
    __shared__ float outs_sm[5 * 16 * 17];            // +1 pad on col
    __shared__ float c_loc[16 * 16];                  // fp32 c state (own cols)
    __shared__ float bias_sm[5 * 16];
    __shared__ int   len_sm[16];

    const int tid    = threadIdx.x;
    const int grp    = blockIdx.x & 3;
    const int member = blockIdx.x >> 2;
    const int wave   = tid >> 6;
    const int lane   = tid & 63;
    const int q      = lane >> 4;   // quad
    const int r16    = lane & 15;   // A: m / B: n / C: col
    const int j0     = member * 16;

    // ---------- preload weights into VGPRs as B-fragments ----------
    // B[k][n]: n = lane&15, k = kk*32 + q*8 + e
    f16x8 bw[24];
    if (wave < 4) {
        const int col = wave * 512 + j0 + r16;   // column in [.,4H] gate matrix
#pragma unroll
        for (int kk = 0; kk < 24; ++kk) {
            f16x8 v;
            const int kbase = kk * 32 + q * 8;
#pragma unroll
            for (int e = 0; e < 8; ++e) {
                const int k = kbase + e;
                const float w = (kk < 16) ? W_all[k * 2048 + col]
                                          : U_all[(k - 512) * 2048 + col];
                v[e] = (f16)w;
            }
            bw[kk] = v;
        }
    } else {
        const int col = j0 + r16;
#pragma unroll
        for (int kk = 0; kk < 16; ++kk) {
            f16x8 v;
            const int kbase = kk * 32 + q * 8;
#pragma unroll
            for (int e = 0; e < 8; ++e) v[e] = (f16)W_d[(kbase + e) * 512 + col];
            bw[kk] = v;
        }
#pragma unroll
        for (int kk = 16; kk < 24; ++kk) bw[kk] = bw[0]; // keep defined
    }

    // ---------- init LDS state ----------
    {
        uint4 z; z.x = z.y = z.z = z.w = 0u;
        uint4* a4 = (uint4*)A_sm;
        uint4* c4 = (uint4*)C_sm;
        for (int i = tid; i < 1024; i += 320) { a4[i] = z; c4[i] = z; }
        if (tid < 256) c_loc[tid] = 0.0f;
        if (tid < 64) {
            const int w = tid >> 4, n = tid & 15;
            const int col = w * 512 + j0 + n;
            bias_sm[w * 16 + n] = b_all[col] + b_u[col];
        } else if (tid < 80) {
            const int n = tid & 15;
            bias_sm[64 + n] = b_d[j0 + n];
        }
        if (tid < 16) len_sm[tid] = lens[grp * 16 + tid];
        // stage x(0) into A_sm kb 64..95
        for (int idx = tid; idx < 1024; idx += 320) {
            const int b = idx >> 6;
            const int kx0 = (idx & 63) << 2;
            const float4 v = *(const float4*)&inputs[(((size_t)(grp * 16 + b)) * S_ + 0) * IN_ + kx0];
            union { f16 h[4]; uint2 u; } p;
            p.h[0] = (f16)v.x; p.h[1] = (f16)v.y; p.h[2] = (f16)v.z; p.h[3] = (f16)v.w;
            const int kb = 64 + (kx0 >> 3), e = kx0 & 7;
            *(uint2*)&A_sm[(kb * 16 + b) * 8 + e] = p.u;
        }
    }
    __syncthreads();

    f16* const hb_g = hbuf + (size_t)grp * 2 * 8192;
    f16* const cb_g = cbuf + (size_t)grp * 2 * 8192;
    unsigned int* const mycnt = cnt + grp * 32;   // 128B-separated counters

    for (int t = 0; t < S_; ++t) {
        // ---------- MFMA phase ----------
        f32x4 acc0 = {0.f, 0.f, 0.f, 0.f}, acc1 = {0.f, 0.f, 0.f, 0.f};
        if (wave < 4) {
            const f16* abase = &A_sm[(q * 16 + r16) * 8];
#pragma unroll
            for (int kk = 0; kk < 24; ++kk) {
                const f16x8 a = *(const f16x8*)(abase + kk * 512);
                if (kk & 1) acc1 = __builtin_amdgcn_mfma_f32_16x16x32_f16(a, bw[kk], acc1, 0, 0, 0);
                else        acc0 = __builtin_amdgcn_mfma_f32_16x16x32_f16(a, bw[kk], acc0, 0, 0, 0);
            }
        } else {
            const f16* abase = &C_sm[(q * 16 + r16) * 8];
#pragma unroll
            for (int kk = 0; kk < 16; ++kk) {
                const f16x8 a = *(const f16x8*)(abase + kk * 512);
                if (kk & 1) acc1 = __builtin_amdgcn_mfma_f32_16x16x32_f16(a, bw[kk], acc1, 0, 0, 0);
                else        acc0 = __builtin_amdgcn_mfma_f32_16x16x32_f16(a, bw[kk], acc0, 0, 0, 0);
            }
        }
        const f32x4 acc = acc0 + acc1;
        // C/D: col = lane&15, row = quad*4 + reg  (row = batch)
#pragma unroll
        for (int r = 0; r < 4; ++r)
            outs_sm[(wave * 16 + q * 4 + r) * 17 + r16] = acc[r];
        __syncthreads();

        // ---------- elementwise gates ----------
        if (tid < 256) {
            const int b = tid >> 4, jj = tid & 15;
            const int gb = grp * 16 + b;
            const float f  = outs_sm[(0 * 16 + b) * 17 + jj] + bias_sm[0  + jj];
            const float i_ = outs_sm[(1 * 16 + b) * 17 + jj] + bias_sm[16 + jj];
            const float o  = outs_sm[(2 * 16 + b) * 17 + jj] + bias_sm[32 + jj];
            const float ct = outs_sm[(3 * 16 + b) * 17 + jj] + bias_sm[48 + jj];
            const float d  = outs_sm[(4 * 16 + b) * 17 + jj] + bias_sm[64 + jj];
            const float ts = tstamps[(size_t)gb * S_ + t];
            const float gt = 1.0f / __logf(ECONST + ts);
            const float cs1   = tanh_f(d);
            const float cprev = c_loc[tid];
            const float cadj  = cprev - cs1 + cs1 * gt;
            const float cnew  = sigf(f) * cadj + sigf(i_) * tanh_f(ct);
            const float hnew  = sigf(o) * tanh_f(cnew);
            c_loc[tid] = cnew;
            const int col = j0 + jj;
            const int len = len_sm[b];
            out0[((size_t)gb * S_ + t) * H_ + col] = (t < len) ? hnew : 0.0f;
            if (t == len - 1) {
                out1[gb * H_ + col] = hnew;
                out2[gb * H_ + col] = cnew;
            }
            // publish f16 slices in the same interleaved layout the copy expects
            const int sl = ((col >> 3) * 16 + b) * 8 + (col & 7);
            f16* const hw = hb_g + (t & 1) * 8192;
            f16* const cw = cb_g + (t & 1) * 8192;
            hw[sl] = (f16)hnew;
            cw[sl] = (f16)cnew;
        }
        __syncthreads();   // drains vmem (stores visible at L2) before barrier

        if (t < S_ - 1) {
            if (tid == 0) {
                // release: writes back local L2 (cross-XCD visibility), then arrive
                __hip_atomic_fetch_add(mycnt, 1u, __ATOMIC_RELEASE, __HIP_MEMORY_SCOPE_AGENT);
                const unsigned int target = 32u * (unsigned)(t + 1);
                while (__hip_atomic_load(mycnt, __ATOMIC_RELAXED, __HIP_MEMORY_SCOPE_AGENT) < target) {}
                __builtin_amdgcn_fence(__ATOMIC_ACQUIRE, "agent"); // inv L1+L2
            } else if (tid >= 64) {
                // prefetch x(t+1) while thread 0 spins (independent data)
                for (int idx = tid - 64; idx < 1024; idx += 256) {
                    const int b = idx >> 6;
                    const int kx0 = (idx & 63) << 2;
                    const float4 v = *(const float4*)&inputs[(((size_t)(grp * 16 + b)) * S_ + (t + 1)) * IN_ + kx0];
                    union { f16 h[4]; uint2 u; } p;
                    p.h[0] = (f16)v.x; p.h[1] = (f16)v.y; p.h[2] = (f16)v.z; p.h[3] = (f16)v.w;
                    const int kb = 64 + (kx0 >> 3), e = kx0 & 7;
                    *(uint2*)&A_sm[(kb * 16 + b) * 8 + e] = p.u;
                }
            }
            __syncthreads();
            // gather full h(t), c(t) for the group (coalesced 16B loads)
            const uint4* hr = (const uint4*)(hb_g + (t & 1) * 8192);
            const uint4* cr = (const uint4*)(cb_g + (t & 1) * 8192);
            uint4* a4 = (uint4*)A_sm;
            uint4* c4 = (uint4*)C_sm;
            for (int i = tid; i < 1024; i += 320) { a4[i] = hr[i]; c4[i] = cr[i]; }
            __syncthreads();
        }
    }
}

extern "C" void kernel_launch(void* const* d_in, const int* in_sizes, int n_in,
                              void* d_out, int out_size, void* d_ws, size_t ws_size,
                              hipStream_t stream) {
    const float* inputs  = (const float*)d_in[0];
    const float* tstamps = (const float*)d_in[1];
    const int*   lens    = (const int*)d_in[2];
    const float* W_all   = (const float*)d_in[3];
    const float* b_all   = (const float*)d_in[4];
    const float* U_all   = (const float*)d_in[5];
    const float* b_u     = (const float*)d_in[6];
    const float* W_d     = (const float*)d_in[7];
    const float* b_d     = (const float*)d_in[8];

    float* out0 = (float*)d_out;                    // [64,1024,512]
    float* out1 = out0 + (size_t)64 * 1024 * 512;   // last_h [64,512]
    float* out2 = out1 + (size_t)64 * 512;          // last_c [64,512]

    char* ws = (char*)d_ws;
    unsigned int* cnt = (unsigned int*)ws;            // 4 counters, 128B apart
    f16* hbuf = (f16*)(ws + 1024);                    // 4 grp * 2 * 8192 f16 = 128KB
    f16* cbuf = (f16*)(ws + 1024 + 131072);           // 128KB

    // barrier counters must start at 0 every call (ws is poisoned 0xAA)
    hipMemsetAsync(ws, 0, 1024, stream);

    tlstm_scan<<<dim3(128), dim3(320), 0, stream>>>(
        inputs, tstamps, lens, W_all, b_all, U_all, b_u, W_d, b_d,
        out0, out1, out2, hbuf, cbuf, cnt);
}